// Round 2
// baseline (980.462 us; speedup 1.0000x reference)
//
#include <hip/hip_runtime.h>
#include <cmath>

typedef _Float16 f16;
typedef _Float16 f16x8 __attribute__((ext_vector_type(8)));
typedef float f32x4 __attribute__((ext_vector_type(4)));

#define NB 8
#define NN 128
#define NT 2048
#define NF 32
#define NLAG 5
#define NH 64
#define NC (NT * NF)  // 65536

// workspace layout (bytes)
#define NA_ELEM (NB * NLAG * NN * NN)  // 655360
#define NW_ELEM (NH * NF)              // 2048
#define OFF_AH 0
#define OFF_AL (NA_ELEM * 2)
#define OFF_WH (NA_ELEM * 4)
#define OFF_WL (OFF_WH + NW_ELEM * 2)

// LDS swizzle: use cl bits 2-3 (vary across a staging wave's lanes AND across
// a B-fragment read's lanes) -> writes ~2 lanes/bank (free), reads at b128
// 8-dword/bank minimum.
#define SWZ(cl) (((cl) >> 2 & 3) << 3)

// ---------------- prep: split A and W into f16 hi/lo planes ----------------
__global__ __launch_bounds__(256) void prep_split(
    const float* __restrict__ A, const float* __restrict__ W,
    f16* __restrict__ Ah, f16* __restrict__ Al,
    f16* __restrict__ Wh, f16* __restrict__ Wl) {
  int idx = blockIdx.x * 256 + threadIdx.x;
  if (idx < NA_ELEM) {
    float v = A[idx];
    f16 h = (f16)v;
    Ah[idx] = h;
    Al[idx] = (f16)(v - (float)h);
  } else if (idx < NA_ELEM + NW_ELEM) {
    int wi = idx - NA_ELEM;
    float v = W[wi];
    f16 h = (f16)v;
    Wh[wi] = h;
    Wl[wi] = (f16)(v - (float)h);
  }
}

// ---------------- fused: lag-GEMM (MFMA, split-f16 3-pass) + Wᵀ + bias + GELU ----------------
// grid: (512 c-blocks, 8 batches), 256 threads (4 waves).
// Tile: 128 i x 128 out-cols; staged x span = 256 cols (128 halo for lags).
__global__ __launch_bounds__(256, 2) void fused_gcn(
    const float* __restrict__ x,    // [8][128][65536] fp32
    const f16* __restrict__ Ah,     // [8][5][128][128]
    const f16* __restrict__ Al,
    const f16* __restrict__ Wh,     // [64][32]
    const f16* __restrict__ Wl,
    const float* __restrict__ bias, // [64]
    float* __restrict__ out) {      // [8][128][2048][64] fp32
  // 64 KB LDS: two 32KB staging buffers (hi plane 16KB + lo plane 16KB each).
  // Staged layout per plane: [c_loc 0..255][j 0..31] f16, 64B rows, XOR slot swizzle.
  __shared__ __attribute__((aligned(16))) f16 lds[32768];

  const int tid = threadIdx.x;
  const int wave = tid >> 6;
  const int lane = tid & 63;
  const int l15 = lane & 15;
  const int lq = lane >> 4;
  const int cb = blockIdx.x;  // 0..511
  const int b = blockIdx.y;   // 0..7
  const int c0 = cb * 128;

  const size_t xbase = (size_t)b * NN * NC;
  // staging: thread covers j = tid>>3, float4 cols (tid&7)+8k
  const int sj = tid >> 3;
  const int sc4 = tid & 7;

  f32x4 acc[2][8];
#pragma unroll
  for (int i = 0; i < 2; ++i)
#pragma unroll
    for (int n = 0; n < 8; ++n) acc[i][n] = (f32x4){0.f, 0.f, 0.f, 0.f};

  // ---- stage chunk 0 into buffer 0
#pragma unroll
  for (int k = 0; k < 8; ++k) {
    const int c4 = sc4 + 8 * k;
    const int cg = c0 - 128 + 4 * c4;
    float4 v;
    if (cg >= 0)
      v = *reinterpret_cast<const float4*>(x + xbase + (size_t)sj * NC + cg);
    else
      v = make_float4(0.f, 0.f, 0.f, 0.f);
    const float vv[4] = {v.x, v.y, v.z, v.w};
#pragma unroll
    for (int e = 0; e < 4; ++e) {
      const int cl = 4 * c4 + e;
      f16 h = (f16)vv[e];
      f16 lo = (f16)(vv[e] - (float)h);
      const int idx = cl * 32 + (sj ^ SWZ(cl));
      lds[idx] = h;
      lds[8192 + idx] = lo;
    }
  }
  __syncthreads();

  f16x8 Bh[8], Bl[8];

  for (int chunk = 0; chunk < 4; ++chunk) {
    const int cur = chunk & 1;
    const int sb = cur * 16384;

    // prefetch next chunk's globals (overlaps with MFMA below)
    float4 pre[8];
    if (chunk < 3) {
#pragma unroll
      for (int k = 0; k < 8; ++k) {
        const int c4 = sc4 + 8 * k;
        const int cg = c0 - 128 + 4 * c4;
        if (cg >= 0)
          pre[k] = *reinterpret_cast<const float4*>(
              x + xbase + (size_t)((chunk + 1) * 32 + sj) * NC + cg);
        else
          pre[k] = make_float4(0.f, 0.f, 0.f, 0.f);
      }
    }

    // initial B-window: m = 8..15 (lag 0)
#pragma unroll
    for (int m = 8; m < 16; ++m) {
      const int cl = 16 * m + l15;
      const int idx = cl * 32 + ((8 * lq) ^ SWZ(cl));
      Bh[m & 7] = *reinterpret_cast<const f16x8*>(&lds[sb + idx]);
      Bl[m & 7] = *reinterpret_cast<const f16x8*>(&lds[sb + 8192 + idx]);
    }

#pragma unroll
    for (int lag = 0; lag < NLAG; ++lag) {
      // A fragments (L2-resident, j-contiguous)
      f16x8 ah[2], al[2];
#pragma unroll
      for (int it = 0; it < 2; ++it) {
        const int i0 = 32 * wave + 16 * it;
        const size_t aoff =
            ((size_t)((b * NLAG + lag) * NN) + i0 + l15) * NN + chunk * 32 + 8 * lq;
        ah[it] = *reinterpret_cast<const f16x8*>(Ah + aoff);
        al[it] = *reinterpret_cast<const f16x8*>(Al + aoff);
      }
      if (lag > 0) {  // slide window: 2 new B tiles
        const int m0 = 8 - 2 * lag;
#pragma unroll
        for (int d = 0; d < 2; ++d) {
          const int m = m0 + d;
          const int cl = 16 * m + l15;
          const int idx = cl * 32 + ((8 * lq) ^ SWZ(cl));
          Bh[m & 7] = *reinterpret_cast<const f16x8*>(&lds[sb + idx]);
          Bl[m & 7] = *reinterpret_cast<const f16x8*>(&lds[sb + 8192 + idx]);
        }
      }
#pragma unroll
      for (int it = 0; it < 2; ++it) {
#pragma unroll
        for (int n = 0; n < 8; ++n) {
          const int m = (n + 8 - 2 * lag) & 7;
          acc[it][n] = __builtin_amdgcn_mfma_f32_16x16x32_f16(ah[it], Bh[m], acc[it][n], 0, 0, 0);
          acc[it][n] = __builtin_amdgcn_mfma_f32_16x16x32_f16(ah[it], Bl[m], acc[it][n], 0, 0, 0);
          acc[it][n] = __builtin_amdgcn_mfma_f32_16x16x32_f16(al[it], Bh[m], acc[it][n], 0, 0, 0);
        }
      }
    }

    // write prefetched chunk into the other buffer
    if (chunk < 3) {
      const int nb = (1 - cur) * 16384;
#pragma unroll
      for (int k = 0; k < 8; ++k) {
        const float vv[4] = {pre[k].x, pre[k].y, pre[k].z, pre[k].w};
#pragma unroll
        for (int e = 0; e < 4; ++e) {
          const int cl = 4 * (sc4 + 8 * k) + e;
          f16 h = (f16)vv[e];
          f16 lo = (f16)(vv[e] - (float)h);
          const int idx = cl * 32 + (sj ^ SWZ(cl));
          lds[nb + idx] = h;
          lds[nb + 8192 + idx] = lo;
        }
      }
    }
    __syncthreads();
  }

  // ---- epilogue: out = gelu(C * W^T + bias), via LDS transpose + 3-pass MFMA
  f16x8 W2h[4], W2l[4];
  float bi4[4];
#pragma unroll
  for (int ht = 0; ht < 4; ++ht) {
    const int woff = (16 * ht + l15) * NF + 8 * lq;
    W2h[ht] = *reinterpret_cast<const f16x8*>(Wh + woff);
    W2l[ht] = *reinterpret_cast<const f16x8*>(Wl + woff);
    bi4[ht] = bias[16 * ht + l15];
  }

  // wave-private scratch: 32 rows x 36 (padded) floats
  float* C1 = reinterpret_cast<float*>(lds) + wave * (32 * 36);

#pragma unroll
  for (int t = 0; t < 4; ++t) {
    // scatter acc slice (out-cols [32t, 32t+32)) into C1[i_local][f]
#pragma unroll
    for (int it = 0; it < 2; ++it) {
#pragma unroll
      for (int dn = 0; dn < 2; ++dn) {
        const int n = 2 * t + dn;
#pragma unroll
        for (int e = 0; e < 4; ++e) {
          const int iw = 16 * it + 4 * lq + e;
          C1[iw * 36 + 16 * dn + l15] = acc[it][n][e];
        }
      }
    }
    // wave-private region + in-order DS ops: no barrier needed
    const int tg = cb * 4 + t;
#pragma unroll
    for (int gl = 0; gl < 2; ++gl) {
      const int row = gl * 16 + l15;
      f32x4 r0 = *reinterpret_cast<const f32x4*>(&C1[row * 36 + 8 * lq]);
      f32x4 r1 = *reinterpret_cast<const f32x4*>(&C1[row * 36 + 8 * lq + 4]);
      f16x8 a2h, a2l;
#pragma unroll
      for (int e = 0; e < 4; ++e) {
        f16 h0 = (f16)r0[e];
        a2h[e] = h0;
        a2l[e] = (f16)(r0[e] - (float)h0);
        f16 h1 = (f16)r1[e];
        a2h[4 + e] = h1;
        a2l[4 + e] = (f16)(r1[e] - (float)h1);
      }
#pragma unroll
      for (int ht = 0; ht < 4; ++ht) {
        f32x4 d = (f32x4){0.f, 0.f, 0.f, 0.f};
        d = __builtin_amdgcn_mfma_f32_16x16x32_f16(a2h, W2h[ht], d, 0, 0, 0);
        d = __builtin_amdgcn_mfma_f32_16x16x32_f16(a2h, W2l[ht], d, 0, 0, 0);
        d = __builtin_amdgcn_mfma_f32_16x16x32_f16(a2l, W2h[ht], d, 0, 0, 0);
#pragma unroll
        for (int e = 0; e < 4; ++e) {
          const float v = d[e] + bi4[ht];
          const float g = 0.5f * v * (1.f + erff(v * 0.70710678118654752f));
          const int ig = 32 * wave + gl * 16 + 4 * lq + e;
          out[(((size_t)b * NN + ig) * NT + tg) * NH + 16 * ht + l15] = g;
        }
      }
    }
  }
}

extern "C" void kernel_launch(void* const* d_in, const int* in_sizes, int n_in,
                              void* d_out, int out_size, void* d_ws, size_t ws_size,
                              hipStream_t stream) {
  const float* x = (const float*)d_in[0];
  const float* A = (const float*)d_in[1];
  const float* W = (const float*)d_in[2];
  const float* bias = (const float*)d_in[3];
  float* out = (float*)d_out;

  char* ws = (char*)d_ws;
  f16* Ah = (f16*)(ws + OFF_AH);
  f16* Al = (f16*)(ws + OFF_AL);
  f16* Wh = (f16*)(ws + OFF_WH);
  f16* Wl = (f16*)(ws + OFF_WL);

  // split A and W into hi/lo f16 planes (2.63 MB of workspace)
  prep_split<<<(NA_ELEM + NW_ELEM + 255) / 256, 256, 0, stream>>>(A, W, Ah, Al, Wh, Wl);

  dim3 grid(NC / 128, NB);
  fused_gcn<<<grid, 256, 0, stream>>>(x, Ah, Al, Wh, Wl, bias, out);
}